// Round 1
// baseline (226.068 us; speedup 1.0000x reference)
//
#include <hip/hip_runtime.h>

#define NG 3200
#define NF 17
#define RH 48
#define RW 88
#define NPIX (RH*RW)      // 4224
#define GTH 192
#define GTW 352
#define NCAM 2
#define CHUNK 200
#define NCHUNK 16         // CHUNK*NCHUNK == NG

// ws layout (float offsets)
#define Z_OFF    0
#define PU_OFF   (Z_OFF + NCAM*NG)            // unsorted params [cam][g][6]
#define PS_OFF   (PU_OFF + NCAM*NG*6)         // sorted params   [cam][r][6]
#define FS_OFF   (PS_OFF + NCAM*NG*6)         // sorted feats    [cam][r][17]
#define PT_OFF   (FS_OFF + NCAM*NG*NF)        // partials [cam][chunk][18][NPIX]
#define ACC_OFF  (PT_OFF + NCAM*NCHUNK*18*NPIX) // 4 floats: num0,den0,num1,den1

// ---------------- Kernel 1: per-(cam,gaussian) projection + conic ----------------
__global__ __launch_bounds__(256) void k_preproc(
    const float* __restrict__ opac, const float* __restrict__ xyz,
    const float* __restrict__ scales, const float* __restrict__ rots,
    const float* __restrict__ vm, const float* __restrict__ intr,
    float* __restrict__ ws)
{
  int idx = blockIdx.x*blockDim.x + threadIdx.x;
  if (idx >= NCAM*NG) return;
  int cam = idx / NG, g = idx % NG;

  // quaternion -> rotation
  float qw=rots[g*4+0], qx=rots[g*4+1], qy=rots[g*4+2], qz=rots[g*4+3];
  float qn = rsqrtf(qw*qw+qx*qx+qy*qy+qz*qz);
  qw*=qn; qx*=qn; qy*=qn; qz*=qn;
  float R[3][3];
  R[0][0]=1.f-2.f*(qy*qy+qz*qz); R[0][1]=2.f*(qx*qy-qw*qz); R[0][2]=2.f*(qx*qz+qw*qy);
  R[1][0]=2.f*(qx*qy+qw*qz); R[1][1]=1.f-2.f*(qx*qx+qz*qz); R[1][2]=2.f*(qy*qz-qw*qx);
  R[2][0]=2.f*(qx*qz-qw*qy); R[2][1]=2.f*(qy*qz+qw*qx); R[2][2]=1.f-2.f*(qx*qx+qy*qy);

  float s2[3];
  #pragma unroll
  for (int k=0;k<3;k++){ float s=expf(scales[g*3+k]); s2[k]=s*s; }

  // cov3d = R diag(s2) R^T
  float M[3][3];
  #pragma unroll
  for(int i=0;i<3;i++)
    #pragma unroll
    for(int j=0;j<3;j++)
      M[i][j] = R[i][0]*s2[0]*R[j][0] + R[i][1]*s2[1]*R[j][1] + R[i][2]*s2[2]*R[j][2];

  const float* Vm = vm + cam*16;
  float Rw[3][3], t[3];
  #pragma unroll
  for(int i=0;i<3;i++){
    #pragma unroll
    for(int j=0;j<3;j++) Rw[i][j]=Vm[i*4+j];
    t[i]=Vm[i*4+3];
  }

  // V = Rw M Rw^T
  float T1[3][3];
  #pragma unroll
  for(int i=0;i<3;i++)
    #pragma unroll
    for(int j=0;j<3;j++)
      T1[i][j] = Rw[i][0]*M[0][j] + Rw[i][1]*M[1][j] + Rw[i][2]*M[2][j];
  float V[3][3];
  #pragma unroll
  for(int i=0;i<3;i++)
    #pragma unroll
    for(int j=0;j<3;j++)
      V[i][j] = T1[i][0]*Rw[j][0] + T1[i][1]*Rw[j][1] + T1[i][2]*Rw[j][2];

  float X=xyz[g*3+0], Y=xyz[g*3+1], Zp=xyz[g*3+2];
  float p0 = Rw[0][0]*X + Rw[0][1]*Y + Rw[0][2]*Zp + t[0];
  float p1 = Rw[1][0]*X + Rw[1][1]*Y + Rw[1][2]*Zp + t[1];
  float p2 = Rw[2][0]*X + Rw[2][1]*Y + Rw[2][2]*Zp + t[2];

  float z  = p2;
  float zc = fmaxf(z, 0.2f);
  float fx=intr[cam*4+0], fy=intr[cam*4+1], cx=intr[cam*4+2], cy=intr[cam*4+3];
  float u = fx*p0/zc + cx;
  float v = fy*p1/zc + cy;

  float j00 = fx/zc, j02 = -fx*p0/(zc*zc);
  float j11 = fy/zc, j12 = -fy*p1/(zc*zc);
  float c00 = j00*j00*V[0][0] + 2.f*j00*j02*V[0][2] + j02*j02*V[2][2];
  float c01 = j00*(V[0][1]*j11 + V[0][2]*j12) + j02*(V[2][1]*j11 + V[2][2]*j12);
  float c11 = j11*j11*V[1][1] + 2.f*j11*j12*V[1][2] + j12*j12*V[2][2];

  float a = c00 + 0.3f, b = c01, c = c11 + 0.3f;
  float det = fmaxf(a*c - b*b, 1e-8f);
  float A = c/det, Bc = -b/det, C = a/det;
  float opv = (z > 0.2f) ? opac[g] : 0.0f;

  ws[Z_OFF + idx] = z;
  float* P = ws + PU_OFF + (size_t)idx*6;
  P[0]=u; P[1]=v; P[2]=A; P[3]=Bc; P[4]=C; P[5]=opv;
}

// ---------------- Kernel 2: stable rank by z + scatter to sorted order ----------------
__global__ __launch_bounds__(256) void k_sort(
    const float* __restrict__ feats, float* __restrict__ ws)
{
  __shared__ float zsh[NG];
  int cam = blockIdx.y;
  for (int i=threadIdx.x; i<NG; i+=blockDim.x) zsh[i] = ws[Z_OFF + cam*NG + i];
  __syncthreads();
  int g = blockIdx.x*blockDim.x + threadIdx.x;
  if (g >= NG) return;
  float zi = zsh[g];
  int rank = 0;
  for (int j=0; j<NG; j++){
    float zj = zsh[j];
    rank += (zj < zi) || (zj == zi && j < g);   // stable tie-break = original index
  }
  const float* src = ws + PU_OFF + (size_t)(cam*NG+g)*6;
  float* dst = ws + PS_OFF + (size_t)(cam*NG+rank)*6;
  #pragma unroll
  for(int k=0;k<6;k++) dst[k]=src[k];
  float* fdst = ws + FS_OFF + (size_t)(cam*NG+rank)*NF;
  #pragma unroll
  for(int k=0;k<NF;k++) fdst[k] = feats[g*NF+k];
}

// ---------------- Kernel 3: chunked front-to-back compositing ----------------
__global__ __launch_bounds__(256) void k_render(float* __restrict__ ws)
{
  __shared__ float sp[CHUNK*6];
  __shared__ float sf[CHUNK*NF];
  int cam = blockIdx.z, chunk = blockIdx.y;
  int g0 = chunk*CHUNK;
  const float* psrc = ws + PS_OFF + (size_t)(cam*NG+g0)*6;
  for (int i=threadIdx.x; i<CHUNK*6; i+=256) sp[i]=psrc[i];
  const float* fsrc = ws + FS_OFF + (size_t)(cam*NG+g0)*NF;
  for (int i=threadIdx.x; i<CHUNK*NF; i+=256) sf[i]=fsrc[i];
  __syncthreads();

  int pix = blockIdx.x*256 + threadIdx.x;
  if (pix >= NPIX) return;
  float px = (float)(pix % RW), py = (float)(pix / RW);

  float T = 1.0f;
  float F[NF];
  #pragma unroll
  for(int k=0;k<NF;k++) F[k]=0.f;

  for (int g=0; g<CHUNK; g++){
    const float* P = sp + g*6;
    float dx = px - P[0], dy = py - P[1];
    float power = -0.5f*(P[2]*dx*dx + P[4]*dy*dy) - P[3]*dx*dy;
    power = fminf(power, 0.f);
    float alpha = fminf(P[5]*__expf(power), 0.99f);
    float w = alpha*T;
    T *= (1.f - alpha);
    const float* f = sf + g*NF;
    #pragma unroll
    for(int k=0;k<NF;k++) F[k] += w*f[k];
  }

  float* out = ws + PT_OFF + (size_t)((cam*NCHUNK+chunk)*18)*NPIX + pix;
  #pragma unroll
  for(int k=0;k<NF;k++) out[k*NPIX]=F[k];
  out[17*NPIX]=T;
}

// ---------------- Kernel 4: combine chunks + masked weighted CE ----------------
__global__ __launch_bounds__(256) void k_loss(
    const int* __restrict__ gt, const int* __restrict__ mask,
    const float* __restrict__ cw, float* __restrict__ ws)
{
  int cam = blockIdx.y;
  int pix = blockIdx.x*256 + threadIdx.x;
  float num = 0.f, den = 0.f;
  if (pix < NPIX) {
    float img[NF];
    #pragma unroll
    for(int k=0;k<NF;k++) img[k]=0.f;
    float Trun = 1.f;
    for (int c=0; c<NCHUNK; c++){
      const float* base = ws + PT_OFF + (size_t)((cam*NCHUNK+c)*18)*NPIX + pix;
      #pragma unroll
      for(int k=0;k<NF;k++) img[k] += Trun*base[k*NPIX];
      Trun *= base[17*NPIX];
    }
    int row = pix / RW, col = pix % RW;
    int gofs = cam*GTH*GTW + (row*4)*GTW + col*4;   // nearest resize: 192/48=352/88=4
    int gi = gt[gofs];
    float mi = (float)mask[gofs];
    float mx = img[0];
    #pragma unroll
    for(int k=1;k<NF;k++) mx = fmaxf(mx, img[k]);
    float s = 0.f;
    #pragma unroll
    for(int k=0;k<NF;k++) s += expf(img[k]-mx);
    float lse = mx + logf(s);
    float nll = lse - img[gi];
    float wi  = cw[gi]*mi;
    num = wi*nll; den = wi;
  }
  #pragma unroll
  for (int off=32; off>0; off>>=1){
    num += __shfl_down(num, off, 64);
    den += __shfl_down(den, off, 64);
  }
  if ((threadIdx.x & 63) == 0){
    atomicAdd(ws + ACC_OFF + cam*2 + 0, num);
    atomicAdd(ws + ACC_OFF + cam*2 + 1, den);
  }
}

// ---------------- Kernel 5: finalize ----------------
__global__ void k_final(const float* __restrict__ ws, float* __restrict__ out)
{
  float l0 = ws[ACC_OFF+0]/fmaxf(ws[ACC_OFF+1], 1e-8f);
  float l1 = ws[ACC_OFF+2]/fmaxf(ws[ACC_OFF+3], 1e-8f);
  out[0] = 0.5f*(l0 + l1);   // (/n_cam)/B with n_cam=2, B=1
}

extern "C" void kernel_launch(void* const* d_in, const int* in_sizes, int n_in,
                              void* d_out, int out_size, void* d_ws, size_t ws_size,
                              hipStream_t stream) {
  const float* vf   = (const float*)d_in[0];  // voxel_feats (1,3200,17)
  const float* op   = (const float*)d_in[1];  // opacity (1,3200,1)
  const float* xyz  = (const float*)d_in[2];  // pc_xyz (3200,3)
  const float* sc   = (const float*)d_in[3];  // scales (3200,3)
  const float* rt   = (const float*)d_in[4];  // rots (3200,4)
  const float* vm   = (const float*)d_in[5];  // viewmats (2,4,4)
  const float* intr = (const float*)d_in[6];  // intrinsics (2,4)
  const float* cw   = (const float*)d_in[7];  // class_weights (17)
  const int*   gt   = (const int*)d_in[8];    // gt_sem (2,192,352)
  const int*   mask = (const int*)d_in[9];    // sem_mask (2,192,352)
  float* ws  = (float*)d_ws;
  float* out = (float*)d_out;

  hipMemsetAsync(ws + ACC_OFF, 0, 4*sizeof(float), stream);
  k_preproc<<<dim3((NCAM*NG+255)/256), 256, 0, stream>>>(op, xyz, sc, rt, vm, intr, ws);
  k_sort   <<<dim3((NG+255)/256, NCAM), 256, 0, stream>>>(vf, ws);
  k_render <<<dim3((NPIX+255)/256, NCHUNK, NCAM), 256, 0, stream>>>(ws);
  k_loss   <<<dim3((NPIX+255)/256, NCAM), 256, 0, stream>>>(gt, mask, cw, ws);
  k_final  <<<1,1,0,stream>>>(ws, out);
}

// Round 2
// 153.362 us; speedup vs baseline: 1.4741x; 1.4741x over previous
//
#include <hip/hip_runtime.h>

#define NG 3200
#define NF 17
#define RH 48
#define RW 88
#define NPIX (RH*RW)      // 4224
#define GTH 192
#define GTW 352
#define NCAM 2
#define CHUNK 200
#define NCHUNK 16         // CHUNK*NCHUNK == NG

// ws layout (float offsets)
#define Z_OFF    0
#define PU_OFF   (Z_OFF + NCAM*NG)            // unsorted params [cam][g][6]
#define PS_OFF   (PU_OFF + NCAM*NG*6)         // sorted params   [cam][r][6]
#define FS_OFF   (PS_OFF + NCAM*NG*6)         // sorted feats    [cam][r][17]
#define PT_OFF   (FS_OFF + NCAM*NG*NF)        // partials [cam][chunk][18][NPIX]
#define ACC_OFF  (PT_OFF + NCAM*NCHUNK*18*NPIX) // 4 floats: num0,den0,num1,den1

// ---------------- Kernel 1: per-(cam,gaussian) projection + conic ----------------
__global__ __launch_bounds__(256) void k_preproc(
    const float* __restrict__ opac, const float* __restrict__ xyz,
    const float* __restrict__ scales, const float* __restrict__ rots,
    const float* __restrict__ vm, const float* __restrict__ intr,
    float* __restrict__ ws)
{
  int idx = blockIdx.x*blockDim.x + threadIdx.x;
  if (idx >= NCAM*NG) return;
  int cam = idx / NG, g = idx % NG;

  // quaternion -> rotation
  float qw=rots[g*4+0], qx=rots[g*4+1], qy=rots[g*4+2], qz=rots[g*4+3];
  float qn = rsqrtf(qw*qw+qx*qx+qy*qy+qz*qz);
  qw*=qn; qx*=qn; qy*=qn; qz*=qn;
  float R[3][3];
  R[0][0]=1.f-2.f*(qy*qy+qz*qz); R[0][1]=2.f*(qx*qy-qw*qz); R[0][2]=2.f*(qx*qz+qw*qy);
  R[1][0]=2.f*(qx*qy+qw*qz); R[1][1]=1.f-2.f*(qx*qx+qz*qz); R[1][2]=2.f*(qy*qz-qw*qx);
  R[2][0]=2.f*(qx*qz-qw*qy); R[2][1]=2.f*(qy*qz+qw*qx); R[2][2]=1.f-2.f*(qx*qx+qy*qy);

  float s2[3];
  #pragma unroll
  for (int k=0;k<3;k++){ float s=expf(scales[g*3+k]); s2[k]=s*s; }

  // cov3d = R diag(s2) R^T
  float M[3][3];
  #pragma unroll
  for(int i=0;i<3;i++)
    #pragma unroll
    for(int j=0;j<3;j++)
      M[i][j] = R[i][0]*s2[0]*R[j][0] + R[i][1]*s2[1]*R[j][1] + R[i][2]*s2[2]*R[j][2];

  const float* Vm = vm + cam*16;
  float Rw[3][3], t[3];
  #pragma unroll
  for(int i=0;i<3;i++){
    #pragma unroll
    for(int j=0;j<3;j++) Rw[i][j]=Vm[i*4+j];
    t[i]=Vm[i*4+3];
  }

  // V = Rw M Rw^T
  float T1[3][3];
  #pragma unroll
  for(int i=0;i<3;i++)
    #pragma unroll
    for(int j=0;j<3;j++)
      T1[i][j] = Rw[i][0]*M[0][j] + Rw[i][1]*M[1][j] + Rw[i][2]*M[2][j];
  float V[3][3];
  #pragma unroll
  for(int i=0;i<3;i++)
    #pragma unroll
    for(int j=0;j<3;j++)
      V[i][j] = T1[i][0]*Rw[j][0] + T1[i][1]*Rw[j][1] + T1[i][2]*Rw[j][2];

  float X=xyz[g*3+0], Y=xyz[g*3+1], Zp=xyz[g*3+2];
  float p0 = Rw[0][0]*X + Rw[0][1]*Y + Rw[0][2]*Zp + t[0];
  float p1 = Rw[1][0]*X + Rw[1][1]*Y + Rw[1][2]*Zp + t[1];
  float p2 = Rw[2][0]*X + Rw[2][1]*Y + Rw[2][2]*Zp + t[2];

  float z  = p2;
  float zc = fmaxf(z, 0.2f);
  float fx=intr[cam*4+0], fy=intr[cam*4+1], cx=intr[cam*4+2], cy=intr[cam*4+3];
  float u = fx*p0/zc + cx;
  float v = fy*p1/zc + cy;

  float j00 = fx/zc, j02 = -fx*p0/(zc*zc);
  float j11 = fy/zc, j12 = -fy*p1/(zc*zc);
  float c00 = j00*j00*V[0][0] + 2.f*j00*j02*V[0][2] + j02*j02*V[2][2];
  float c01 = j00*(V[0][1]*j11 + V[0][2]*j12) + j02*(V[2][1]*j11 + V[2][2]*j12);
  float c11 = j11*j11*V[1][1] + 2.f*j11*j12*V[1][2] + j12*j12*V[2][2];

  float a = c00 + 0.3f, b = c01, c = c11 + 0.3f;
  float det = fmaxf(a*c - b*b, 1e-8f);
  float A = c/det, Bc = -b/det, C = a/det;
  float opv = (z > 0.2f) ? opac[g] : 0.0f;

  ws[Z_OFF + idx] = z;
  float* P = ws + PU_OFF + (size_t)idx*6;
  P[0]=u; P[1]=v; P[2]=A; P[3]=Bc; P[4]=C; P[5]=opv;
}

// ---------------- Kernel 2: stable rank by z (one WAVE per gaussian) + scatter ----------------
// rank[g] = #{ j : z[j] < z[g] || (z[j]==z[g] && j < g) }  == stable argsort position.
// 4 gaussians per 256-thread block; each lane counts a 50-element slice (j = k*64+lane,
// stride-1 across lanes -> 2 lanes/bank, conflict-free), then 6-step shuffle reduce.
__global__ __launch_bounds__(256) void k_sort(
    const float* __restrict__ feats, float* __restrict__ ws)
{
  __shared__ float zsh[NG];
  int cam = blockIdx.y;
  for (int i=threadIdx.x; i<NG; i+=256) zsh[i] = ws[Z_OFF + cam*NG + i];
  __syncthreads();

  int wave = threadIdx.x >> 6, lane = threadIdx.x & 63;
  int g = blockIdx.x*4 + wave;          // grid.x = NG/4 = 800
  float zi = zsh[g];
  int rank = 0;
  #pragma unroll 5
  for (int k=0; k<NG/64; k++){
    int j = k*64 + lane;
    float zj = zsh[j];
    rank += ((zj < zi) || (zj == zi && j < g)) ? 1 : 0;
  }
  #pragma unroll
  for (int off=32; off>0; off>>=1) rank += __shfl_down(rank, off, 64);
  rank = __shfl(rank, 0, 64);

  // lane-parallel scatter to sorted order
  const float* src = ws + PU_OFF + (size_t)(cam*NG+g)*6;
  if (lane < 6) (ws + PS_OFF + (size_t)(cam*NG+rank)*6)[lane] = src[lane];
  if (lane < NF) (ws + FS_OFF + (size_t)(cam*NG+rank)*NF)[lane] = feats[g*NF+lane];
}

// ---------------- Kernel 3: chunked front-to-back compositing ----------------
__global__ __launch_bounds__(256) void k_render(float* __restrict__ ws)
{
  __shared__ float sp[CHUNK*6];
  __shared__ float sf[CHUNK*NF];
  int cam = blockIdx.z, chunk = blockIdx.y;
  int g0 = chunk*CHUNK;
  const float* psrc = ws + PS_OFF + (size_t)(cam*NG+g0)*6;
  for (int i=threadIdx.x; i<CHUNK*6; i+=256) sp[i]=psrc[i];
  const float* fsrc = ws + FS_OFF + (size_t)(cam*NG+g0)*NF;
  for (int i=threadIdx.x; i<CHUNK*NF; i+=256) sf[i]=fsrc[i];
  __syncthreads();

  int pix = blockIdx.x*256 + threadIdx.x;
  if (pix >= NPIX) return;
  float px = (float)(pix % RW), py = (float)(pix / RW);

  float T = 1.0f;
  float F[NF];
  #pragma unroll
  for(int k=0;k<NF;k++) F[k]=0.f;

  for (int g=0; g<CHUNK; g++){
    const float* P = sp + g*6;
    float dx = px - P[0], dy = py - P[1];
    float power = -0.5f*(P[2]*dx*dx + P[4]*dy*dy) - P[3]*dx*dy;
    power = fminf(power, 0.f);
    float alpha = fminf(P[5]*__expf(power), 0.99f);
    float w = alpha*T;
    T *= (1.f - alpha);
    const float* f = sf + g*NF;
    #pragma unroll
    for(int k=0;k<NF;k++) F[k] += w*f[k];
  }

  float* out = ws + PT_OFF + (size_t)((cam*NCHUNK+chunk)*18)*NPIX + pix;
  #pragma unroll
  for(int k=0;k<NF;k++) out[k*NPIX]=F[k];
  out[17*NPIX]=T;
}

// ---------------- Kernel 4: combine chunks + masked weighted CE ----------------
__global__ __launch_bounds__(256) void k_loss(
    const int* __restrict__ gt, const int* __restrict__ mask,
    const float* __restrict__ cw, float* __restrict__ ws)
{
  int cam = blockIdx.y;
  int pix = blockIdx.x*256 + threadIdx.x;
  float num = 0.f, den = 0.f;
  if (pix < NPIX) {
    float img[NF];
    #pragma unroll
    for(int k=0;k<NF;k++) img[k]=0.f;
    float Trun = 1.f;
    for (int c=0; c<NCHUNK; c++){
      const float* base = ws + PT_OFF + (size_t)((cam*NCHUNK+c)*18)*NPIX + pix;
      #pragma unroll
      for(int k=0;k<NF;k++) img[k] += Trun*base[k*NPIX];
      Trun *= base[17*NPIX];
    }
    int row = pix / RW, col = pix % RW;
    int gofs = cam*GTH*GTW + (row*4)*GTW + col*4;   // nearest resize: 192/48=352/88=4
    int gi = gt[gofs];
    float mi = (float)mask[gofs];
    float mx = img[0];
    #pragma unroll
    for(int k=1;k<NF;k++) mx = fmaxf(mx, img[k]);
    float s = 0.f;
    #pragma unroll
    for(int k=0;k<NF;k++) s += expf(img[k]-mx);
    float lse = mx + logf(s);
    float nll = lse - img[gi];
    float wi  = cw[gi]*mi;
    num = wi*nll; den = wi;
  }
  #pragma unroll
  for (int off=32; off>0; off>>=1){
    num += __shfl_down(num, off, 64);
    den += __shfl_down(den, off, 64);
  }
  if ((threadIdx.x & 63) == 0){
    atomicAdd(ws + ACC_OFF + cam*2 + 0, num);
    atomicAdd(ws + ACC_OFF + cam*2 + 1, den);
  }
}

// ---------------- Kernel 5: finalize ----------------
__global__ void k_final(const float* __restrict__ ws, float* __restrict__ out)
{
  float l0 = ws[ACC_OFF+0]/fmaxf(ws[ACC_OFF+1], 1e-8f);
  float l1 = ws[ACC_OFF+2]/fmaxf(ws[ACC_OFF+3], 1e-8f);
  out[0] = 0.5f*(l0 + l1);   // (/n_cam)/B with n_cam=2, B=1
}

extern "C" void kernel_launch(void* const* d_in, const int* in_sizes, int n_in,
                              void* d_out, int out_size, void* d_ws, size_t ws_size,
                              hipStream_t stream) {
  const float* vf   = (const float*)d_in[0];  // voxel_feats (1,3200,17)
  const float* op   = (const float*)d_in[1];  // opacity (1,3200,1)
  const float* xyz  = (const float*)d_in[2];  // pc_xyz (3200,3)
  const float* sc   = (const float*)d_in[3];  // scales (3200,3)
  const float* rt   = (const float*)d_in[4];  // rots (3200,4)
  const float* vm   = (const float*)d_in[5];  // viewmats (2,4,4)
  const float* intr = (const float*)d_in[6];  // intrinsics (2,4)
  const float* cw   = (const float*)d_in[7];  // class_weights (17)
  const int*   gt   = (const int*)d_in[8];    // gt_sem (2,192,352)
  const int*   mask = (const int*)d_in[9];    // sem_mask (2,192,352)
  float* ws  = (float*)d_ws;
  float* out = (float*)d_out;

  hipMemsetAsync(ws + ACC_OFF, 0, 4*sizeof(float), stream);
  k_preproc<<<dim3((NCAM*NG+255)/256), 256, 0, stream>>>(op, xyz, sc, rt, vm, intr, ws);
  k_sort   <<<dim3(NG/4, NCAM), 256, 0, stream>>>(vf, ws);
  k_render <<<dim3((NPIX+255)/256, NCHUNK, NCAM), 256, 0, stream>>>(ws);
  k_loss   <<<dim3((NPIX+255)/256, NCAM), 256, 0, stream>>>(gt, mask, cw, ws);
  k_final  <<<1,1,0,stream>>>(ws, out);
}

// Round 3
// 152.867 us; speedup vs baseline: 1.4789x; 1.0032x over previous
//
#include <hip/hip_runtime.h>

#define NG 3200
#define NF 17
#define NFP 18            // padded feature stride (8B-aligned float2)
#define RH 48
#define RW 88
#define NPIX (RH*RW)      // 4224
#define GTH 192
#define GTW 352
#define NCAM 2
#define CHUNK 64
#define NCHUNK 50         // CHUNK*NCHUNK == NG
#define GPC 5             // chunks per group
#define NGROUP 10         // NCHUNK/GPC

typedef float v2f __attribute__((ext_vector_type(2)));

// ws layout (float offsets)
#define Z_OFF    0
#define PU_OFF   (Z_OFF + NCAM*NG)              // unsorted params [cam][g][6]
#define PS_OFF   (PU_OFF + NCAM*NG*6)           // sorted params   [cam][r][6]
#define FS_OFF   (PS_OFF + NCAM*NG*6)           // sorted feats    [cam][r][18] (pad=0)
#define PT_OFF   (FS_OFF + NCAM*NG*NFP)         // partials [cam][chunk][18][NPIX]
#define GP_OFF   (PT_OFF + NCAM*NCHUNK*18*NPIX) // groups   [cam][group][18][NPIX]
#define ACC_OFF  (GP_OFF + NCAM*NGROUP*18*NPIX) // 4 floats: num0,den0,num1,den1

// ---------------- Kernel 1: per-(cam,gaussian) projection + conic ----------------
__global__ __launch_bounds__(256) void k_preproc(
    const float* __restrict__ opac, const float* __restrict__ xyz,
    const float* __restrict__ scales, const float* __restrict__ rots,
    const float* __restrict__ vm, const float* __restrict__ intr,
    float* __restrict__ ws)
{
  int idx = blockIdx.x*blockDim.x + threadIdx.x;
  if (idx >= NCAM*NG) return;
  int cam = idx / NG, g = idx % NG;

  float qw=rots[g*4+0], qx=rots[g*4+1], qy=rots[g*4+2], qz=rots[g*4+3];
  float qn = rsqrtf(qw*qw+qx*qx+qy*qy+qz*qz);
  qw*=qn; qx*=qn; qy*=qn; qz*=qn;
  float R[3][3];
  R[0][0]=1.f-2.f*(qy*qy+qz*qz); R[0][1]=2.f*(qx*qy-qw*qz); R[0][2]=2.f*(qx*qz+qw*qy);
  R[1][0]=2.f*(qx*qy+qw*qz); R[1][1]=1.f-2.f*(qx*qx+qz*qz); R[1][2]=2.f*(qy*qz-qw*qx);
  R[2][0]=2.f*(qx*qz-qw*qy); R[2][1]=2.f*(qy*qz+qw*qx); R[2][2]=1.f-2.f*(qx*qx+qy*qy);

  float s2[3];
  #pragma unroll
  for (int k=0;k<3;k++){ float s=expf(scales[g*3+k]); s2[k]=s*s; }

  float M[3][3];
  #pragma unroll
  for(int i=0;i<3;i++)
    #pragma unroll
    for(int j=0;j<3;j++)
      M[i][j] = R[i][0]*s2[0]*R[j][0] + R[i][1]*s2[1]*R[j][1] + R[i][2]*s2[2]*R[j][2];

  const float* Vm = vm + cam*16;
  float Rw[3][3], t[3];
  #pragma unroll
  for(int i=0;i<3;i++){
    #pragma unroll
    for(int j=0;j<3;j++) Rw[i][j]=Vm[i*4+j];
    t[i]=Vm[i*4+3];
  }

  float T1[3][3];
  #pragma unroll
  for(int i=0;i<3;i++)
    #pragma unroll
    for(int j=0;j<3;j++)
      T1[i][j] = Rw[i][0]*M[0][j] + Rw[i][1]*M[1][j] + Rw[i][2]*M[2][j];
  float V[3][3];
  #pragma unroll
  for(int i=0;i<3;i++)
    #pragma unroll
    for(int j=0;j<3;j++)
      V[i][j] = T1[i][0]*Rw[j][0] + T1[i][1]*Rw[j][1] + T1[i][2]*Rw[j][2];

  float X=xyz[g*3+0], Y=xyz[g*3+1], Zp=xyz[g*3+2];
  float p0 = Rw[0][0]*X + Rw[0][1]*Y + Rw[0][2]*Zp + t[0];
  float p1 = Rw[1][0]*X + Rw[1][1]*Y + Rw[1][2]*Zp + t[1];
  float p2 = Rw[2][0]*X + Rw[2][1]*Y + Rw[2][2]*Zp + t[2];

  float z  = p2;
  float zc = fmaxf(z, 0.2f);
  float fx=intr[cam*4+0], fy=intr[cam*4+1], cx=intr[cam*4+2], cy=intr[cam*4+3];
  float u = fx*p0/zc + cx;
  float v = fy*p1/zc + cy;

  float j00 = fx/zc, j02 = -fx*p0/(zc*zc);
  float j11 = fy/zc, j12 = -fy*p1/(zc*zc);
  float c00 = j00*j00*V[0][0] + 2.f*j00*j02*V[0][2] + j02*j02*V[2][2];
  float c01 = j00*(V[0][1]*j11 + V[0][2]*j12) + j02*(V[2][1]*j11 + V[2][2]*j12);
  float c11 = j11*j11*V[1][1] + 2.f*j11*j12*V[1][2] + j12*j12*V[2][2];

  float a = c00 + 0.3f, b = c01, c = c11 + 0.3f;
  float det = fmaxf(a*c - b*b, 1e-8f);
  float A = c/det, Bc = -b/det, C = a/det;
  float opv = (z > 0.2f) ? opac[g] : 0.0f;

  ws[Z_OFF + idx] = z;
  float* P = ws + PU_OFF + (size_t)idx*6;
  P[0]=u; P[1]=v; P[2]=A; P[3]=Bc; P[4]=C; P[5]=opv;
}

// ---------------- Kernel 2: stable rank by z (one WAVE per gaussian) + scatter ----------------
__global__ __launch_bounds__(256) void k_sort(
    const float* __restrict__ feats, float* __restrict__ ws)
{
  __shared__ float zsh[NG];
  int cam = blockIdx.y;
  for (int i=threadIdx.x; i<NG; i+=256) zsh[i] = ws[Z_OFF + cam*NG + i];
  __syncthreads();

  int wave = threadIdx.x >> 6, lane = threadIdx.x & 63;
  int g = blockIdx.x*4 + wave;          // grid.x = NG/4 = 800
  float zi = zsh[g];
  int rank = 0;
  #pragma unroll 5
  for (int k=0; k<NG/64; k++){
    int j = k*64 + lane;
    float zj = zsh[j];
    rank += ((zj < zi) || (zj == zi && j < g)) ? 1 : 0;
  }
  #pragma unroll
  for (int off=32; off>0; off>>=1) rank += __shfl_down(rank, off, 64);
  rank = __shfl(rank, 0, 64);

  const float* src = ws + PU_OFF + (size_t)(cam*NG+g)*6;
  if (lane < 6) (ws + PS_OFF + (size_t)(cam*NG+rank)*6)[lane] = src[lane];
  if (lane < NFP) (ws + FS_OFF + (size_t)(cam*NG+rank)*NFP)[lane] =
                     (lane < NF) ? feats[g*NF+lane] : 0.0f;
}

// ---------------- Kernel 3: chunked front-to-back compositing ----------------
__global__ __launch_bounds__(256) void k_render(float* __restrict__ ws)
{
  __shared__ float sp[CHUNK*6];
  __shared__ v2f   sf2[CHUNK*(NFP/2)];   // 8B-aligned padded feats
  int cam = blockIdx.z, chunk = blockIdx.y;
  int g0 = chunk*CHUNK;
  const float* psrc = ws + PS_OFF + (size_t)(cam*NG+g0)*6;
  for (int i=threadIdx.x; i<CHUNK*6; i+=256) sp[i]=psrc[i];
  const float* fsrc = ws + FS_OFF + (size_t)(cam*NG+g0)*NFP;
  float* sff = (float*)sf2;
  for (int i=threadIdx.x; i<CHUNK*NFP; i+=256) sff[i]=fsrc[i];
  __syncthreads();

  int pix = blockIdx.x*256 + threadIdx.x;
  if (pix >= NPIX) return;
  float px = (float)(pix % RW), py = (float)(pix / RW);

  float T = 1.0f;
  v2f F2[9];
  #pragma unroll
  for(int k=0;k<9;k++) F2[k]=(v2f)(0.f);

  #pragma unroll 4
  for (int g=0; g<CHUNK; g++){
    const float* P = sp + g*6;
    float dx = px - P[0], dy = py - P[1];
    float power = -0.5f*(P[2]*dx*dx + P[4]*dy*dy) - P[3]*dx*dy;
    power = fminf(power, 0.f);
    float alpha = fminf(P[5]*__expf(power), 0.99f);
    float w = alpha*T;
    T *= (1.f - alpha);
    v2f w2; w2.x = w; w2.y = w;
    const v2f* f2 = sf2 + g*(NFP/2);
    #pragma unroll
    for(int k=0;k<9;k++) F2[k] += w2*f2[k];   // v_pk_fma_f32
  }

  float* out = ws + PT_OFF + (size_t)((cam*NCHUNK+chunk)*18)*NPIX + pix;
  const float* Ff = (const float*)F2;
  #pragma unroll
  for(int k=0;k<NF;k++) out[k*NPIX]=Ff[k];
  out[17*NPIX]=T;
}

// ---------------- Kernel 3b: combine GPC chunks -> one group partial ----------------
__global__ __launch_bounds__(256) void k_combine(float* __restrict__ ws)
{
  int cam = blockIdx.z, grp = blockIdx.y;
  int pix = blockIdx.x*256 + threadIdx.x;
  if (pix >= NPIX) return;
  float F[NF];
  #pragma unroll
  for(int k=0;k<NF;k++) F[k]=0.f;
  float T = 1.f;
  for (int c=grp*GPC; c<grp*GPC+GPC; c++){
    const float* base = ws + PT_OFF + (size_t)((cam*NCHUNK+c)*18)*NPIX + pix;
    #pragma unroll
    for(int k=0;k<NF;k++) F[k] += T*base[k*NPIX];
    T *= base[17*NPIX];
  }
  float* out = ws + GP_OFF + (size_t)((cam*NGROUP+grp)*18)*NPIX + pix;
  #pragma unroll
  for(int k=0;k<NF;k++) out[k*NPIX]=F[k];
  out[17*NPIX]=T;
}

// ---------------- Kernel 4: combine groups + masked weighted CE ----------------
__global__ __launch_bounds__(256) void k_loss(
    const int* __restrict__ gt, const int* __restrict__ mask,
    const float* __restrict__ cw, float* __restrict__ ws)
{
  int cam = blockIdx.y;
  int pix = blockIdx.x*256 + threadIdx.x;
  float num = 0.f, den = 0.f;
  if (pix < NPIX) {
    float img[NF];
    #pragma unroll
    for(int k=0;k<NF;k++) img[k]=0.f;
    float Trun = 1.f;
    for (int c=0; c<NGROUP; c++){
      const float* base = ws + GP_OFF + (size_t)((cam*NGROUP+c)*18)*NPIX + pix;
      #pragma unroll
      for(int k=0;k<NF;k++) img[k] += Trun*base[k*NPIX];
      Trun *= base[17*NPIX];
    }
    int row = pix / RW, col = pix % RW;
    int gofs = cam*GTH*GTW + (row*4)*GTW + col*4;   // nearest resize: factor 4
    int gi = gt[gofs];
    float mi = (float)mask[gofs];
    float mx = img[0];
    #pragma unroll
    for(int k=1;k<NF;k++) mx = fmaxf(mx, img[k]);
    float s = 0.f;
    #pragma unroll
    for(int k=0;k<NF;k++) s += expf(img[k]-mx);
    float lse = mx + logf(s);
    float nll = lse - img[gi];
    float wi  = cw[gi]*mi;
    num = wi*nll; den = wi;
  }
  #pragma unroll
  for (int off=32; off>0; off>>=1){
    num += __shfl_down(num, off, 64);
    den += __shfl_down(den, off, 64);
  }
  if ((threadIdx.x & 63) == 0){
    atomicAdd(ws + ACC_OFF + cam*2 + 0, num);
    atomicAdd(ws + ACC_OFF + cam*2 + 1, den);
  }
}

// ---------------- Kernel 5: finalize ----------------
__global__ void k_final(const float* __restrict__ ws, float* __restrict__ out)
{
  float l0 = ws[ACC_OFF+0]/fmaxf(ws[ACC_OFF+1], 1e-8f);
  float l1 = ws[ACC_OFF+2]/fmaxf(ws[ACC_OFF+3], 1e-8f);
  out[0] = 0.5f*(l0 + l1);   // (/n_cam)/B with n_cam=2, B=1
}

extern "C" void kernel_launch(void* const* d_in, const int* in_sizes, int n_in,
                              void* d_out, int out_size, void* d_ws, size_t ws_size,
                              hipStream_t stream) {
  const float* vf   = (const float*)d_in[0];
  const float* op   = (const float*)d_in[1];
  const float* xyz  = (const float*)d_in[2];
  const float* sc   = (const float*)d_in[3];
  const float* rt   = (const float*)d_in[4];
  const float* vm   = (const float*)d_in[5];
  const float* intr = (const float*)d_in[6];
  const float* cw   = (const float*)d_in[7];
  const int*   gt   = (const int*)d_in[8];
  const int*   mask = (const int*)d_in[9];
  float* ws  = (float*)d_ws;
  float* out = (float*)d_out;

  hipMemsetAsync(ws + ACC_OFF, 0, 4*sizeof(float), stream);
  k_preproc<<<dim3((NCAM*NG+255)/256), 256, 0, stream>>>(op, xyz, sc, rt, vm, intr, ws);
  k_sort   <<<dim3(NG/4, NCAM), 256, 0, stream>>>(vf, ws);
  k_render <<<dim3((NPIX+255)/256, NCHUNK, NCAM), 256, 0, stream>>>(ws);
  k_combine<<<dim3((NPIX+255)/256, NGROUP, NCAM), 256, 0, stream>>>(ws);
  k_loss   <<<dim3((NPIX+255)/256, NCAM), 256, 0, stream>>>(gt, mask, cw, ws);
  k_final  <<<1,1,0,stream>>>(ws, out);
}

// Round 4
// 130.487 us; speedup vs baseline: 1.7325x; 1.1715x over previous
//
#include <hip/hip_runtime.h>

#define NG 3200
#define NF 17
#define NFP 18            // padded feature stride
#define RH 48
#define RW 88
#define NPIX (RH*RW)      // 4224
#define GTH 192
#define GTW 352
#define NCAM 2
#define CHUNK 64
#define NCHUNK 50         // CHUNK*NCHUNK == NG
#define GPC 5             // chunks per group
#define NGROUP 10         // NCHUNK/GPC
#define NPL 9             // packed half2 planes: (F0,F1)...(F14,F15),(F16,T)

typedef float v2f __attribute__((ext_vector_type(2)));
typedef _Float16 h2 __attribute__((ext_vector_type(2)));

// ws layout (float/dword offsets)
#define Z_OFF    0
#define PU_OFF   (Z_OFF + NCAM*NG)               // unsorted params [cam][g][6]
#define PS_OFF   (PU_OFF + NCAM*NG*6)            // sorted params   [cam][r][6]
#define FS_OFF   (PS_OFF + NCAM*NG*6)            // sorted feats    [cam][r][18] (pad=0)
#define PT_OFF   (FS_OFF + NCAM*NG*NFP)          // partials [cam][chunk][9 h2-planes][NPIX]
#define GP_OFF   (PT_OFF + NCAM*NCHUNK*NPL*NPIX) // groups   [cam][group][9 h2-planes][NPIX]
#define ACC_OFF  (GP_OFF + NCAM*NGROUP*NPL*NPIX) // 4 floats: num0,den0,num1,den1

// ---------------- Kernel 1: per-(cam,gaussian) projection + conic ----------------
__global__ __launch_bounds__(256) void k_preproc(
    const float* __restrict__ opac, const float* __restrict__ xyz,
    const float* __restrict__ scales, const float* __restrict__ rots,
    const float* __restrict__ vm, const float* __restrict__ intr,
    float* __restrict__ ws)
{
  int idx = blockIdx.x*blockDim.x + threadIdx.x;
  if (idx < 4) ws[ACC_OFF + idx] = 0.0f;     // zero loss accumulators (replaces memset)
  if (idx >= NCAM*NG) return;
  int cam = idx / NG, g = idx % NG;

  float qw=rots[g*4+0], qx=rots[g*4+1], qy=rots[g*4+2], qz=rots[g*4+3];
  float qn = rsqrtf(qw*qw+qx*qx+qy*qy+qz*qz);
  qw*=qn; qx*=qn; qy*=qn; qz*=qn;
  float R[3][3];
  R[0][0]=1.f-2.f*(qy*qy+qz*qz); R[0][1]=2.f*(qx*qy-qw*qz); R[0][2]=2.f*(qx*qz+qw*qy);
  R[1][0]=2.f*(qx*qy+qw*qz); R[1][1]=1.f-2.f*(qx*qx+qz*qz); R[1][2]=2.f*(qy*qz-qw*qx);
  R[2][0]=2.f*(qx*qz-qw*qy); R[2][1]=2.f*(qy*qz+qw*qx); R[2][2]=1.f-2.f*(qx*qx+qy*qy);

  float s2[3];
  #pragma unroll
  for (int k=0;k<3;k++){ float s=expf(scales[g*3+k]); s2[k]=s*s; }

  float M[3][3];
  #pragma unroll
  for(int i=0;i<3;i++)
    #pragma unroll
    for(int j=0;j<3;j++)
      M[i][j] = R[i][0]*s2[0]*R[j][0] + R[i][1]*s2[1]*R[j][1] + R[i][2]*s2[2]*R[j][2];

  const float* Vm = vm + cam*16;
  float Rw[3][3], t[3];
  #pragma unroll
  for(int i=0;i<3;i++){
    #pragma unroll
    for(int j=0;j<3;j++) Rw[i][j]=Vm[i*4+j];
    t[i]=Vm[i*4+3];
  }

  float T1[3][3];
  #pragma unroll
  for(int i=0;i<3;i++)
    #pragma unroll
    for(int j=0;j<3;j++)
      T1[i][j] = Rw[i][0]*M[0][j] + Rw[i][1]*M[1][j] + Rw[i][2]*M[2][j];
  float V[3][3];
  #pragma unroll
  for(int i=0;i<3;i++)
    #pragma unroll
    for(int j=0;j<3;j++)
      V[i][j] = T1[i][0]*Rw[j][0] + T1[i][1]*Rw[j][1] + T1[i][2]*Rw[j][2];

  float X=xyz[g*3+0], Y=xyz[g*3+1], Zp=xyz[g*3+2];
  float p0 = Rw[0][0]*X + Rw[0][1]*Y + Rw[0][2]*Zp + t[0];
  float p1 = Rw[1][0]*X + Rw[1][1]*Y + Rw[1][2]*Zp + t[1];
  float p2 = Rw[2][0]*X + Rw[2][1]*Y + Rw[2][2]*Zp + t[2];

  float z  = p2;
  float zc = fmaxf(z, 0.2f);
  float fx=intr[cam*4+0], fy=intr[cam*4+1], cx=intr[cam*4+2], cy=intr[cam*4+3];
  float u = fx*p0/zc + cx;
  float v = fy*p1/zc + cy;

  float j00 = fx/zc, j02 = -fx*p0/(zc*zc);
  float j11 = fy/zc, j12 = -fy*p1/(zc*zc);
  float c00 = j00*j00*V[0][0] + 2.f*j00*j02*V[0][2] + j02*j02*V[2][2];
  float c01 = j00*(V[0][1]*j11 + V[0][2]*j12) + j02*(V[2][1]*j11 + V[2][2]*j12);
  float c11 = j11*j11*V[1][1] + 2.f*j11*j12*V[1][2] + j12*j12*V[2][2];

  float a = c00 + 0.3f, b = c01, c = c11 + 0.3f;
  float det = fmaxf(a*c - b*b, 1e-8f);
  // conic pre-scaled by -0.5*log2(e) so render does power2 = A2 dx^2 + C2 dy^2 + B2 dx dy
  // with alpha = opac * exp2(min(power2,0))  (exp2 monotone -> min commutes with scaling)
  const float L2E = 1.4426950408889634f;
  float A2 = -0.5f*L2E * (c/det);
  float B2 = -L2E * (-b/det);
  float C2 = -0.5f*L2E * (a/det);
  float opv = (z > 0.2f) ? opac[g] : 0.0f;

  ws[Z_OFF + idx] = z;
  float* P = ws + PU_OFF + (size_t)idx*6;
  P[0]=u; P[1]=v; P[2]=A2; P[3]=B2; P[4]=C2; P[5]=opv;
}

// ---------------- Kernel 2: stable rank by z (one WAVE per gaussian) + scatter ----------------
__global__ __launch_bounds__(256) void k_sort(
    const float* __restrict__ feats, float* __restrict__ ws)
{
  __shared__ float zsh[NG];
  int cam = blockIdx.y;
  for (int i=threadIdx.x; i<NG; i+=256) zsh[i] = ws[Z_OFF + cam*NG + i];
  __syncthreads();

  int wave = threadIdx.x >> 6, lane = threadIdx.x & 63;
  int g = blockIdx.x*4 + wave;          // grid.x = NG/4 = 800
  float zi = zsh[g];
  int rank = 0;
  #pragma unroll 5
  for (int k=0; k<NG/64; k++){
    int j = k*64 + lane;
    float zj = zsh[j];
    rank += ((zj < zi) || (zj == zi && j < g)) ? 1 : 0;
  }
  #pragma unroll
  for (int off=32; off>0; off>>=1) rank += __shfl_down(rank, off, 64);
  rank = __shfl(rank, 0, 64);

  const float* src = ws + PU_OFF + (size_t)(cam*NG+g)*6;
  if (lane < 6) (ws + PS_OFF + (size_t)(cam*NG+rank)*6)[lane] = src[lane];
  if (lane < NFP) (ws + FS_OFF + (size_t)(cam*NG+rank)*NFP)[lane] =
                     (lane < NF) ? feats[g*NF+lane] : 0.0f;
}

// ---------------- Kernel 3: chunked front-to-back compositing (fp16 partials) ----------------
__global__ __launch_bounds__(192) void k_render(float* __restrict__ ws)
{
  __shared__ float sp[CHUNK*6];
  __shared__ v2f   sf2[CHUNK*(NFP/2)];
  int cam = blockIdx.z, chunk = blockIdx.y;
  int g0 = chunk*CHUNK;
  const float* psrc = ws + PS_OFF + (size_t)(cam*NG+g0)*6;
  for (int i=threadIdx.x; i<CHUNK*6; i+=192) sp[i]=psrc[i];
  const float* fsrc = ws + FS_OFF + (size_t)(cam*NG+g0)*NFP;
  float* sff = (float*)sf2;
  for (int i=threadIdx.x; i<CHUNK*NFP; i+=192) sff[i]=fsrc[i];
  __syncthreads();

  int pix = blockIdx.x*192 + threadIdx.x;       // 22*192 == NPIX exactly, no guard
  float px = (float)(pix % RW), py = (float)(pix / RW);

  float T = 1.0f;
  v2f F2[9];
  #pragma unroll
  for(int k=0;k<9;k++) F2[k]=(v2f)(0.f);

  #pragma unroll 4
  for (int g=0; g<CHUNK; g++){
    const float* P = sp + g*6;
    float dx = px - P[0], dy = py - P[1];
    float m1 = P[2]*dx;                   // A2*dx
    float m2 = fmaf(P[3], dy, m1);        // + B2*dy
    float m3 = dx*m2;
    float power2 = fmaf(P[4]*dy, dy, m3); // + C2*dy^2   (already scaled by -0.5*log2e)
    power2 = fminf(power2, 0.f);
    float alpha = fminf(P[5]*exp2f(power2), 0.99f);
    float w = alpha*T;
    T = fmaf(-alpha, T, T);               // T *= (1-alpha)
    v2f w2; w2.x = w; w2.y = w;
    const v2f* f2 = sf2 + g*(NFP/2);
    #pragma unroll
    for(int k=0;k<9;k++) F2[k] += w2*f2[k];   // v_pk_fma_f32
  }

  const float* Ff = (const float*)F2;
  h2* out = (h2*)(ws + PT_OFF) + (size_t)((cam*NCHUNK+chunk)*NPL)*NPIX + pix;
  #pragma unroll
  for(int k=0;k<8;k++){
    h2 v; v.x = (_Float16)Ff[2*k]; v.y = (_Float16)Ff[2*k+1];
    out[k*NPIX] = v;
  }
  { h2 v; v.x = (_Float16)Ff[16]; v.y = (_Float16)T; out[8*NPIX] = v; }
}

// ---------------- Kernel 3b: combine GPC chunks -> one group partial ----------------
__global__ __launch_bounds__(192) void k_combine(float* __restrict__ ws)
{
  int cam = blockIdx.z, grp = blockIdx.y;
  int pix = blockIdx.x*192 + threadIdx.x;
  float F[NF];
  #pragma unroll
  for(int k=0;k<NF;k++) F[k]=0.f;
  float T = 1.f;
  for (int c=grp*GPC; c<grp*GPC+GPC; c++){
    const h2* base = (const h2*)(ws + PT_OFF) + (size_t)((cam*NCHUNK+c)*NPL)*NPIX + pix;
    h2 v[9];
    #pragma unroll
    for(int k=0;k<9;k++) v[k] = base[k*NPIX];
    #pragma unroll
    for(int k=0;k<8;k++){ F[2*k] += T*(float)v[k].x; F[2*k+1] += T*(float)v[k].y; }
    F[16] += T*(float)v[8].x;
    T *= (float)v[8].y;
  }
  h2* out = (h2*)(ws + GP_OFF) + (size_t)((cam*NGROUP+grp)*NPL)*NPIX + pix;
  #pragma unroll
  for(int k=0;k<8;k++){
    h2 v; v.x = (_Float16)F[2*k]; v.y = (_Float16)F[2*k+1];
    out[k*NPIX] = v;
  }
  { h2 v; v.x = (_Float16)F[16]; v.y = (_Float16)T; out[8*NPIX] = v; }
}

// ---------------- Kernel 4: combine groups + masked weighted CE ----------------
__global__ __launch_bounds__(192) void k_loss(
    const int* __restrict__ gt, const int* __restrict__ mask,
    const float* __restrict__ cw, float* __restrict__ ws)
{
  int cam = blockIdx.y;
  int pix = blockIdx.x*192 + threadIdx.x;
  float img[NF];
  #pragma unroll
  for(int k=0;k<NF;k++) img[k]=0.f;
  float Trun = 1.f;
  for (int c=0; c<NGROUP; c++){
    const h2* base = (const h2*)(ws + GP_OFF) + (size_t)((cam*NGROUP+c)*NPL)*NPIX + pix;
    h2 v[9];
    #pragma unroll
    for(int k=0;k<9;k++) v[k] = base[k*NPIX];
    #pragma unroll
    for(int k=0;k<8;k++){ img[2*k] += Trun*(float)v[k].x; img[2*k+1] += Trun*(float)v[k].y; }
    img[16] += Trun*(float)v[8].x;
    Trun *= (float)v[8].y;
  }
  int row = pix / RW, col = pix % RW;
  int gofs = cam*GTH*GTW + (row*4)*GTW + col*4;   // nearest resize: factor 4
  int gi = gt[gofs];
  float mi = (float)mask[gofs];
  float mx = img[0];
  #pragma unroll
  for(int k=1;k<NF;k++) mx = fmaxf(mx, img[k]);
  float s = 0.f;
  #pragma unroll
  for(int k=0;k<NF;k++) s += expf(img[k]-mx);
  float lse = mx + logf(s);
  float nll = lse - img[gi];
  float wi  = cw[gi]*mi;
  float num = wi*nll, den = wi;
  #pragma unroll
  for (int off=32; off>0; off>>=1){
    num += __shfl_down(num, off, 64);
    den += __shfl_down(den, off, 64);
  }
  if ((threadIdx.x & 63) == 0){
    atomicAdd(ws + ACC_OFF + cam*2 + 0, num);
    atomicAdd(ws + ACC_OFF + cam*2 + 1, den);
  }
}

// ---------------- Kernel 5: finalize ----------------
__global__ void k_final(const float* __restrict__ ws, float* __restrict__ out)
{
  float l0 = ws[ACC_OFF+0]/fmaxf(ws[ACC_OFF+1], 1e-8f);
  float l1 = ws[ACC_OFF+2]/fmaxf(ws[ACC_OFF+3], 1e-8f);
  out[0] = 0.5f*(l0 + l1);   // (/n_cam)/B with n_cam=2, B=1
}

extern "C" void kernel_launch(void* const* d_in, const int* in_sizes, int n_in,
                              void* d_out, int out_size, void* d_ws, size_t ws_size,
                              hipStream_t stream) {
  const float* vf   = (const float*)d_in[0];
  const float* op   = (const float*)d_in[1];
  const float* xyz  = (const float*)d_in[2];
  const float* sc   = (const float*)d_in[3];
  const float* rt   = (const float*)d_in[4];
  const float* vm   = (const float*)d_in[5];
  const float* intr = (const float*)d_in[6];
  const float* cw   = (const float*)d_in[7];
  const int*   gt   = (const int*)d_in[8];
  const int*   mask = (const int*)d_in[9];
  float* ws  = (float*)d_ws;
  float* out = (float*)d_out;

  k_preproc<<<dim3((NCAM*NG+255)/256), 256, 0, stream>>>(op, xyz, sc, rt, vm, intr, ws);
  k_sort   <<<dim3(NG/4, NCAM), 256, 0, stream>>>(vf, ws);
  k_render <<<dim3(NPIX/192, NCHUNK, NCAM), 192, 0, stream>>>(ws);
  k_combine<<<dim3(NPIX/192, NGROUP, NCAM), 192, 0, stream>>>(ws);
  k_loss   <<<dim3(NPIX/192, NCAM), 192, 0, stream>>>(gt, mask, cw, ws);
  k_final  <<<1,1,0,stream>>>(ws, out);
}

// Round 5
// 125.894 us; speedup vs baseline: 1.7957x; 1.0365x over previous
//
#include <hip/hip_runtime.h>

#define NG 3200
#define NF 17
#define NFP 18            // padded feature stride
#define RH 48
#define RW 88
#define NPIX (RH*RW)      // 4224
#define GTH 192
#define GTW 352
#define NCAM 2
#define CHUNK 80
#define NCHUNK 40         // CHUNK*NCHUNK == NG
#define NPL 9             // packed half2 planes: (F0,F1)...(F14,F15),(F16,T)
#define CPW 5             // chunks per wave in k_loss (NCHUNK/8)
#define NLOSSBLK (NPIX/64*NCAM)   // 132

typedef float v2f __attribute__((ext_vector_type(2)));
typedef _Float16 h2 __attribute__((ext_vector_type(2)));

// ws layout (float/dword offsets)
#define Z_OFF    0
#define PU_OFF   (Z_OFF + NCAM*NG)               // unsorted params [cam][g][6]
#define PS_OFF   (PU_OFF + NCAM*NG*6)            // sorted params   [cam][r][6]
#define FS_OFF   (PS_OFF + NCAM*NG*6)            // sorted feats    [cam][r][18] (pad=0)
#define PT_OFF   (FS_OFF + NCAM*NG*NFP)          // partials [cam][chunk][9 h2-planes][NPIX]
#define ACC_OFF  (PT_OFF + NCAM*NCHUNK*NPL*NPIX) // num0,den0,num1,den1,ticket

// ---------------- Kernel 1: per-(cam,gaussian) projection + conic ----------------
__global__ __launch_bounds__(256) void k_preproc(
    const float* __restrict__ opac, const float* __restrict__ xyz,
    const float* __restrict__ scales, const float* __restrict__ rots,
    const float* __restrict__ vm, const float* __restrict__ intr,
    float* __restrict__ ws)
{
  int idx = blockIdx.x*blockDim.x + threadIdx.x;
  if (idx < 8) ws[ACC_OFF + idx] = 0.0f;     // zero loss accumulators + ticket
  if (idx >= NCAM*NG) return;
  int cam = idx / NG, g = idx % NG;

  float qw=rots[g*4+0], qx=rots[g*4+1], qy=rots[g*4+2], qz=rots[g*4+3];
  float qn = rsqrtf(qw*qw+qx*qx+qy*qy+qz*qz);
  qw*=qn; qx*=qn; qy*=qn; qz*=qn;
  float R[3][3];
  R[0][0]=1.f-2.f*(qy*qy+qz*qz); R[0][1]=2.f*(qx*qy-qw*qz); R[0][2]=2.f*(qx*qz+qw*qy);
  R[1][0]=2.f*(qx*qy+qw*qz); R[1][1]=1.f-2.f*(qx*qx+qz*qz); R[1][2]=2.f*(qy*qz-qw*qx);
  R[2][0]=2.f*(qx*qz-qw*qy); R[2][1]=2.f*(qy*qz+qw*qx); R[2][2]=1.f-2.f*(qx*qx+qy*qy);

  float s2[3];
  #pragma unroll
  for (int k=0;k<3;k++){ float s=expf(scales[g*3+k]); s2[k]=s*s; }

  float M[3][3];
  #pragma unroll
  for(int i=0;i<3;i++)
    #pragma unroll
    for(int j=0;j<3;j++)
      M[i][j] = R[i][0]*s2[0]*R[j][0] + R[i][1]*s2[1]*R[j][1] + R[i][2]*s2[2]*R[j][2];

  const float* Vm = vm + cam*16;
  float Rw[3][3], t[3];
  #pragma unroll
  for(int i=0;i<3;i++){
    #pragma unroll
    for(int j=0;j<3;j++) Rw[i][j]=Vm[i*4+j];
    t[i]=Vm[i*4+3];
  }

  float T1[3][3];
  #pragma unroll
  for(int i=0;i<3;i++)
    #pragma unroll
    for(int j=0;j<3;j++)
      T1[i][j] = Rw[i][0]*M[0][j] + Rw[i][1]*M[1][j] + Rw[i][2]*M[2][j];
  float V[3][3];
  #pragma unroll
  for(int i=0;i<3;i++)
    #pragma unroll
    for(int j=0;j<3;j++)
      V[i][j] = T1[i][0]*Rw[j][0] + T1[i][1]*Rw[j][1] + T1[i][2]*Rw[j][2];

  float X=xyz[g*3+0], Y=xyz[g*3+1], Zp=xyz[g*3+2];
  float p0 = Rw[0][0]*X + Rw[0][1]*Y + Rw[0][2]*Zp + t[0];
  float p1 = Rw[1][0]*X + Rw[1][1]*Y + Rw[1][2]*Zp + t[1];
  float p2 = Rw[2][0]*X + Rw[2][1]*Y + Rw[2][2]*Zp + t[2];

  float z  = p2;
  float zc = fmaxf(z, 0.2f);
  float fx=intr[cam*4+0], fy=intr[cam*4+1], cx=intr[cam*4+2], cy=intr[cam*4+3];
  float u = fx*p0/zc + cx;
  float v = fy*p1/zc + cy;

  float j00 = fx/zc, j02 = -fx*p0/(zc*zc);
  float j11 = fy/zc, j12 = -fy*p1/(zc*zc);
  float c00 = j00*j00*V[0][0] + 2.f*j00*j02*V[0][2] + j02*j02*V[2][2];
  float c01 = j00*(V[0][1]*j11 + V[0][2]*j12) + j02*(V[2][1]*j11 + V[2][2]*j12);
  float c11 = j11*j11*V[1][1] + 2.f*j11*j12*V[1][2] + j12*j12*V[2][2];

  float a = c00 + 0.3f, b = c01, c = c11 + 0.3f;
  float det = fmaxf(a*c - b*b, 1e-8f);
  // conic pre-scaled by -0.5*log2(e): power2 = A2 dx^2 + B2 dx dy + C2 dy^2,
  // alpha = opac * exp2(min(power2,0))  (exp2 monotone -> min commutes)
  const float L2E = 1.4426950408889634f;
  float A2 = -0.5f*L2E * (c/det);
  float B2 = -L2E * (-b/det);
  float C2 = -0.5f*L2E * (a/det);
  float opv = (z > 0.2f) ? opac[g] : 0.0f;

  ws[Z_OFF + idx] = z;
  float* P = ws + PU_OFF + (size_t)idx*6;
  P[0]=u; P[1]=v; P[2]=A2; P[3]=B2; P[4]=C2; P[5]=opv;
}

// ---------------- Kernel 2: stable rank by z (one WAVE per gaussian) + scatter ----------------
__global__ __launch_bounds__(256) void k_sort(
    const float* __restrict__ feats, float* __restrict__ ws)
{
  __shared__ float zsh[NG];
  int cam = blockIdx.y;
  for (int i=threadIdx.x; i<NG; i+=256) zsh[i] = ws[Z_OFF + cam*NG + i];
  __syncthreads();

  int wave = threadIdx.x >> 6, lane = threadIdx.x & 63;
  int g = blockIdx.x*4 + wave;          // grid.x = NG/4 = 800
  float zi = zsh[g];
  int rank = 0;
  #pragma unroll 5
  for (int k=0; k<NG/64; k++){
    int j = k*64 + lane;
    float zj = zsh[j];
    rank += ((zj < zi) || (zj == zi && j < g)) ? 1 : 0;
  }
  #pragma unroll
  for (int off=32; off>0; off>>=1) rank += __shfl_down(rank, off, 64);
  rank = __shfl(rank, 0, 64);

  const float* src = ws + PU_OFF + (size_t)(cam*NG+g)*6;
  if (lane < 6) (ws + PS_OFF + (size_t)(cam*NG+rank)*6)[lane] = src[lane];
  if (lane < NFP) (ws + FS_OFF + (size_t)(cam*NG+rank)*NFP)[lane] =
                     (lane < NF) ? feats[g*NF+lane] : 0.0f;
}

// ---------------- Kernel 3: chunked front-to-back compositing (fp16 partials) ----------------
__global__ __launch_bounds__(192) void k_render(float* __restrict__ ws)
{
  __shared__ float sp[CHUNK*6];
  __shared__ v2f   sf2[CHUNK*(NFP/2)];
  int cam = blockIdx.z, chunk = blockIdx.y;
  int g0 = chunk*CHUNK;
  const float* psrc = ws + PS_OFF + (size_t)(cam*NG+g0)*6;
  for (int i=threadIdx.x; i<CHUNK*6; i+=192) sp[i]=psrc[i];
  const float* fsrc = ws + FS_OFF + (size_t)(cam*NG+g0)*NFP;
  float* sff = (float*)sf2;
  for (int i=threadIdx.x; i<CHUNK*NFP; i+=192) sff[i]=fsrc[i];
  __syncthreads();

  int pix = blockIdx.x*192 + threadIdx.x;       // 22*192 == NPIX exactly, no guard
  float px = (float)(pix % RW), py = (float)(pix / RW);

  float T = 1.0f;
  v2f F2[9];
  #pragma unroll
  for(int k=0;k<9;k++) F2[k]=(v2f)(0.f);

  #pragma unroll 4
  for (int g=0; g<CHUNK; g++){
    const float* P = sp + g*6;
    float dx = px - P[0], dy = py - P[1];
    float m1 = P[2]*dx;                   // A2*dx
    float m2 = fmaf(P[3], dy, m1);        // + B2*dy
    float m3 = dx*m2;
    float power2 = fmaf(P[4]*dy, dy, m3); // + C2*dy^2
    power2 = fminf(power2, 0.f);
    float alpha = fminf(P[5]*exp2f(power2), 0.99f);
    float w = alpha*T;
    T = fmaf(-alpha, T, T);               // T *= (1-alpha)
    v2f w2; w2.x = w; w2.y = w;
    const v2f* f2 = sf2 + g*(NFP/2);
    #pragma unroll
    for(int k=0;k<9;k++) F2[k] += w2*f2[k];   // v_pk_fma_f32
  }

  const float* Ff = (const float*)F2;
  h2* out = (h2*)(ws + PT_OFF) + (size_t)((cam*NCHUNK+chunk)*NPL)*NPIX + pix;
  #pragma unroll
  for(int k=0;k<8;k++){
    h2 v; v.x = (_Float16)Ff[2*k]; v.y = (_Float16)Ff[2*k+1];
    out[k*NPIX] = v;
  }
  { h2 v; v.x = (_Float16)Ff[16]; v.y = (_Float16)T; out[8*NPIX] = v; }
}

// ---------------- Kernel 4: fused combine + masked weighted CE + finalize ----------------
// 64 pixels/block (1 per lane), 8 waves; wave w combines chunks [w*5, w*5+5) in
// registers, parks (F,T) in LDS (stride 19 = conflict-free), wave 0 merges the
// 8 partials front-to-back, computes CE, reduces, atomically accumulates; the
// last block (ticket) computes the final scalar loss.
__global__ __launch_bounds__(512) void k_loss(
    const int* __restrict__ gt, const int* __restrict__ mask,
    const float* __restrict__ cw, float* __restrict__ ws, float* __restrict__ out)
{
  __shared__ float part[8*64*19];
  int cam = blockIdx.y;
  int wave = threadIdx.x >> 6, lane = threadIdx.x & 63;
  int pix = blockIdx.x*64 + lane;

  float F[NF];
  #pragma unroll
  for(int k=0;k<NF;k++) F[k]=0.f;
  float T = 1.f;
  #pragma unroll
  for (int i=0;i<CPW;i++){
    int c = wave*CPW + i;
    const h2* base = (const h2*)(ws + PT_OFF) + (size_t)((cam*NCHUNK+c)*NPL)*NPIX + pix;
    h2 v[9];
    #pragma unroll
    for(int k=0;k<9;k++) v[k] = base[k*NPIX];
    #pragma unroll
    for(int k=0;k<8;k++){ F[2*k] += T*(float)v[k].x; F[2*k+1] += T*(float)v[k].y; }
    F[16] += T*(float)v[8].x;
    T *= (float)v[8].y;
  }
  float* p = part + (wave*64 + lane)*19;
  #pragma unroll
  for(int k=0;k<NF;k++) p[k]=F[k];
  p[17]=T;
  __syncthreads();

  if (wave == 0){
    float img[NF];
    #pragma unroll
    for(int k=0;k<NF;k++) img[k]=0.f;
    float Trun = 1.f;
    for (int w=0; w<8; w++){
      const float* b = part + (w*64 + lane)*19;
      #pragma unroll
      for(int k=0;k<NF;k++) img[k] += Trun*b[k];
      Trun *= b[17];
    }
    int row = pix / RW, col = pix % RW;
    int gofs = cam*GTH*GTW + (row*4)*GTW + col*4;   // nearest resize: factor 4
    int gi = gt[gofs];
    float mi = (float)mask[gofs];
    float mx = img[0];
    #pragma unroll
    for(int k=1;k<NF;k++) mx = fmaxf(mx, img[k]);
    float s = 0.f;
    #pragma unroll
    for(int k=0;k<NF;k++) s += expf(img[k]-mx);
    float lse = mx + logf(s);
    float nll = lse - img[gi];
    float wi  = cw[gi]*mi;
    float num = wi*nll, den = wi;
    #pragma unroll
    for (int off=32; off>0; off>>=1){
      num += __shfl_down(num, off, 64);
      den += __shfl_down(den, off, 64);
    }
    if (lane == 0){
      atomicAdd(ws + ACC_OFF + cam*2 + 0, num);
      atomicAdd(ws + ACC_OFF + cam*2 + 1, den);
      __threadfence();
      int ticket = (int)atomicAdd(ws + ACC_OFF + 4, 1.0f);
      if (ticket == NLOSSBLK-1){
        // last block: all accumulators globally visible; read via atomic RMW
        float n0 = atomicAdd(ws + ACC_OFF + 0, 0.f);
        float d0 = atomicAdd(ws + ACC_OFF + 1, 0.f);
        float n1 = atomicAdd(ws + ACC_OFF + 2, 0.f);
        float d1 = atomicAdd(ws + ACC_OFF + 3, 0.f);
        float l0 = n0/fmaxf(d0, 1e-8f);
        float l1 = n1/fmaxf(d1, 1e-8f);
        out[0] = 0.5f*(l0 + l1);
      }
    }
  }
}

extern "C" void kernel_launch(void* const* d_in, const int* in_sizes, int n_in,
                              void* d_out, int out_size, void* d_ws, size_t ws_size,
                              hipStream_t stream) {
  const float* vf   = (const float*)d_in[0];
  const float* op   = (const float*)d_in[1];
  const float* xyz  = (const float*)d_in[2];
  const float* sc   = (const float*)d_in[3];
  const float* rt   = (const float*)d_in[4];
  const float* vm   = (const float*)d_in[5];
  const float* intr = (const float*)d_in[6];
  const float* cw   = (const float*)d_in[7];
  const int*   gt   = (const int*)d_in[8];
  const int*   mask = (const int*)d_in[9];
  float* ws  = (float*)d_ws;
  float* out = (float*)d_out;

  k_preproc<<<dim3((NCAM*NG+255)/256), 256, 0, stream>>>(op, xyz, sc, rt, vm, intr, ws);
  k_sort   <<<dim3(NG/4, NCAM), 256, 0, stream>>>(vf, ws);
  k_render <<<dim3(NPIX/192, NCHUNK, NCAM), 192, 0, stream>>>(ws);
  k_loss   <<<dim3(NPIX/64, NCAM), 512, 0, stream>>>(gt, mask, cw, ws, out);
}